// Round 1
// baseline (2280.994 us; speedup 1.0000x reference)
//
#include <hip/hip_runtime.h>
#include <math.h>

// Problem constants (B=2, S=2048, H=2048, NH=16, KVH=4, D=128, layer_idx=5)
//   q    = hs @ w_q^T + b_q
//   attn = causal_softmax(q k^T / sqrt(128)) v       (per head, GQA 4:1)
//   out  = attn @ w_proj^T + b_proj
// Masked logits = -65504*6 (finite; exp underflows to exactly 0, matching ref).

#define RSQ128 0.08838834764831845f   /* 1/sqrt(128) == scale_factor*unscale */
#define MASK6  (-393024.0f)           /* MASK_VALUE * (LAYER_IDX+1) */

// ---------------------------------------------------------------------------
// NT GEMM + bias: C[m,n] = sum_k A[m,k]*W[n,k] + bias[n]
// 128x128 block tile, 8x8 per thread, K-tile 8, k-transposed LDS for b128 reads
// ---------------------------------------------------------------------------
__global__ __launch_bounds__(256, 2) void gemm_nt_bias(
    const float* __restrict__ A,    // [M,K] row-major
    const float* __restrict__ W,    // [N,K] row-major
    const float* __restrict__ bias, // [N]
    float* __restrict__ C,          // [M,N]
    int M, int N, int K)
{
    __shared__ __align__(16) float At[8][132];  // [k][m], pad 132: 2-way max
    __shared__ __align__(16) float Wt[8][132];  // [k][n]
    const int tid = threadIdx.x;
    const int tx = tid & 15, ty = tid >> 4;
    const int m0 = blockIdx.y * 128, n0 = blockIdx.x * 128;
    const int lrow = tid >> 1;          // 0..127
    const int lk4  = (tid & 1) * 4;     // 0 or 4
    const float* Ap = A + (size_t)(m0 + lrow) * K + lk4;
    const float* Wp = W + (size_t)(n0 + lrow) * K + lk4;

    float acc[8][8];
#pragma unroll
    for (int i = 0; i < 8; ++i)
#pragma unroll
        for (int j = 0; j < 8; ++j) acc[i][j] = 0.f;

    for (int k0 = 0; k0 < K; k0 += 8) {
        const float4 av = *(const float4*)(Ap + k0);
        const float4 wv = *(const float4*)(Wp + k0);
        __syncthreads();   // previous compute done before overwrite
        At[lk4 + 0][lrow] = av.x; At[lk4 + 1][lrow] = av.y;
        At[lk4 + 2][lrow] = av.z; At[lk4 + 3][lrow] = av.w;
        Wt[lk4 + 0][lrow] = wv.x; Wt[lk4 + 1][lrow] = wv.y;
        Wt[lk4 + 2][lrow] = wv.z; Wt[lk4 + 3][lrow] = wv.w;
        __syncthreads();
#pragma unroll
        for (int kk = 0; kk < 8; ++kk) {
            const float4 a0 = *(const float4*)&At[kk][ty * 4];
            const float4 a1 = *(const float4*)&At[kk][64 + ty * 4];
            const float4 w0 = *(const float4*)&Wt[kk][tx * 4];
            const float4 w1 = *(const float4*)&Wt[kk][64 + tx * 4];
            const float a[8] = {a0.x, a0.y, a0.z, a0.w, a1.x, a1.y, a1.z, a1.w};
            const float w[8] = {w0.x, w0.y, w0.z, w0.w, w1.x, w1.y, w1.z, w1.w};
#pragma unroll
            for (int i = 0; i < 8; ++i)
#pragma unroll
                for (int j = 0; j < 8; ++j)
                    acc[i][j] += a[i] * w[j];
        }
    }

#pragma unroll
    for (int i = 0; i < 8; ++i) {
        const int r = m0 + ((i < 4) ? (ty * 4 + i) : (64 + ty * 4 + (i - 4)));
#pragma unroll
        for (int half = 0; half < 2; ++half) {
            const int c = n0 + half * 64 + tx * 4;
            float4 o;
            o.x = acc[i][half * 4 + 0] + bias[c + 0];
            o.y = acc[i][half * 4 + 1] + bias[c + 1];
            o.z = acc[i][half * 4 + 2] + bias[c + 2];
            o.w = acc[i][half * 4 + 3] + bias[c + 3];
            *(float4*)(C + (size_t)r * N + c) = o;
        }
    }
}

// ---------------------------------------------------------------------------
// Flash attention, fp32, causal, GQA 4:1.
// Block: 64 query rows x one (b,h). 256 threads (16x16), scores 4x4/thread
// (rows ty*4+i, cols tx+16*j), O 4x8/thread (cols tx*4 and 64+tx*4).
// LDS: Qs (reused for P) + KVs (K then V) = exactly 64 KB.
// All tiles stored swizzled: element [r][c] at r*128 + ((c + 4r) & 127)
// -> every read/write pattern is <=2-way bank aliasing (free).
// Row reductions: the 16 threads of a score row are contiguous lanes ->
// __shfl_xor width=16. m/l state in registers (replicated across tx).
// ---------------------------------------------------------------------------
__global__ __launch_bounds__(256, 2) void attn_flash(
    const float* __restrict__ Qg,   // [B*S, H]
    const float* __restrict__ Kg,   // [B,KVH,S,D]
    const float* __restrict__ Vg,   // [B,KVH,S,D]
    float* __restrict__ Og)         // [B*S, H]
{
    __shared__ __align__(16) float Qs[64 * 128];   // Q tile, then P tile
    __shared__ __align__(16) float KVs[64 * 128];  // K tile, then V tile
    const int tid = threadIdx.x;
    const int tx = tid & 15, ty = tid >> 4;
    const int s0 = blockIdx.x * 64;
    const int bh = blockIdx.y;
    const int b = bh >> 4, h = bh & 15, kh = h >> 2;
    const float* Qb = Qg + (size_t)(b * 2048 + s0) * 2048 + h * 128;
    const float* Kb = Kg + (size_t)(b * 4 + kh) * 2048 * 128;
    const float* Vb = Vg + (size_t)(b * 4 + kh) * 2048 * 128;

    float accO[4][8];
    float mrow[4], lrow[4];
#pragma unroll
    for (int i = 0; i < 4; ++i) {
        mrow[i] = -INFINITY; lrow[i] = 0.f;
#pragma unroll
        for (int j = 0; j < 8; ++j) accO[i][j] = 0.f;
    }

    for (int t0 = 0; t0 <= s0; t0 += 64) {
        __syncthreads();   // prev iteration PV reads done
        // ---- stage Q tile + K tile (swizzled) ----
#pragma unroll
        for (int rep = 0; rep < 8; ++rep) {
            const int f = rep * 256 + tid;      // 0..2047
            const int r = f >> 5;               // 0..63
            const int d4 = (f & 31) * 4;        // 0..124
            const float4 qv = *(const float4*)(Qb + (size_t)r * 2048 + d4);
            const float4 kv = *(const float4*)(Kb + (size_t)(t0 + r) * 128 + d4);
            const int cs = (d4 + 4 * r) & 127;
            *(float4*)&Qs[r * 128 + cs] = qv;
            *(float4*)&KVs[r * 128 + cs] = kv;
        }
        __syncthreads();

        // ---- Sc = Q K^T ----
        float sc[4][4];
#pragma unroll
        for (int i = 0; i < 4; ++i)
#pragma unroll
            for (int j = 0; j < 4; ++j) sc[i][j] = 0.f;

#pragma unroll 4
        for (int d4 = 0; d4 < 128; d4 += 4) {
            float4 q4[4], k4[4];
#pragma unroll
            for (int i = 0; i < 4; ++i) {
                const int r = ty * 4 + i;
                q4[i] = *(const float4*)&Qs[r * 128 + ((d4 + 4 * r) & 127)];
            }
#pragma unroll
            for (int j = 0; j < 4; ++j) {
                const int t = tx + 16 * j;
                k4[j] = *(const float4*)&KVs[t * 128 + ((d4 + 4 * t) & 127)];
            }
#pragma unroll
            for (int i = 0; i < 4; ++i)
#pragma unroll
                for (int j = 0; j < 4; ++j)
                    sc[i][j] += q4[i].x * k4[j].x + q4[i].y * k4[j].y +
                                q4[i].z * k4[j].z + q4[i].w * k4[j].w;
        }

        // ---- causal mask + scale, row max ----
        float pm[4];
#pragma unroll
        for (int i = 0; i < 4; ++i) {
            const int rg = s0 + ty * 4 + i;
#pragma unroll
            for (int j = 0; j < 4; ++j) {
                const int tg = t0 + tx + 16 * j;
                sc[i][j] = (tg <= rg) ? sc[i][j] * RSQ128 : MASK6;
            }
            pm[i] = fmaxf(fmaxf(sc[i][0], sc[i][1]), fmaxf(sc[i][2], sc[i][3]));
        }
#pragma unroll
        for (int off = 1; off < 16; off <<= 1)
#pragma unroll
            for (int i = 0; i < 4; ++i)
                pm[i] = fmaxf(pm[i], __shfl_xor(pm[i], off, 16));

        // ---- online softmax state update ----
        float alpha;
#pragma unroll
        for (int i = 0; i < 4; ++i) {
            const float mn = fmaxf(mrow[i], pm[i]);   // finite (MASK6 finite)
            alpha = __expf(mrow[i] - mn);             // 0 on first block
            mrow[i] = mn;
            lrow[i] *= alpha;
#pragma unroll
            for (int j = 0; j < 8; ++j) accO[i][j] *= alpha;
        }

        __syncthreads();   // all Q/K LDS reads complete

        // ---- P = exp(sc - m) into Qs region; stage V into KVs ----
        float ps[4];
#pragma unroll
        for (int i = 0; i < 4; ++i) {
            const int r = ty * 4 + i;
            float s = 0.f;
#pragma unroll
            for (int j = 0; j < 4; ++j) {
                const float p = __expf(sc[i][j] - mrow[i]);
                s += p;
                const int t = tx + 16 * j;
                Qs[r * 128 + ((t + 4 * r) & 127)] = p;
            }
            ps[i] = s;
        }
#pragma unroll
        for (int off = 1; off < 16; off <<= 1)
#pragma unroll
            for (int i = 0; i < 4; ++i)
                ps[i] += __shfl_xor(ps[i], off, 16);
#pragma unroll
        for (int i = 0; i < 4; ++i) lrow[i] += ps[i];

#pragma unroll
        for (int rep = 0; rep < 8; ++rep) {
            const int f = rep * 256 + tid;
            const int r = f >> 5;
            const int d4 = (f & 31) * 4;
            const float4 vv = *(const float4*)(Vb + (size_t)(t0 + r) * 128 + d4);
            *(float4*)&KVs[r * 128 + ((d4 + 4 * r) & 127)] = vv;
        }
        __syncthreads();

        // ---- O += P V ----
#pragma unroll 4
        for (int t = 0; t < 64; ++t) {
            float pv[4];
#pragma unroll
            for (int i = 0; i < 4; ++i) {
                const int r = ty * 4 + i;
                pv[i] = Qs[r * 128 + ((t + 4 * r) & 127)];
            }
            const float4 v0 = *(const float4*)&KVs[t * 128 + ((tx * 4 + 4 * t) & 127)];
            const float4 v1 = *(const float4*)&KVs[t * 128 + ((64 + tx * 4 + 4 * t) & 127)];
#pragma unroll
            for (int i = 0; i < 4; ++i) {
                accO[i][0] += pv[i] * v0.x; accO[i][1] += pv[i] * v0.y;
                accO[i][2] += pv[i] * v0.z; accO[i][3] += pv[i] * v0.w;
                accO[i][4] += pv[i] * v1.x; accO[i][5] += pv[i] * v1.y;
                accO[i][6] += pv[i] * v1.z; accO[i][7] += pv[i] * v1.w;
            }
        }
    }

    // ---- epilogue: O / l ----
#pragma unroll
    for (int i = 0; i < 4; ++i) {
        const int r = s0 + ty * 4 + i;
        const float inv = 1.0f / lrow[i];
        float* orow = Og + (size_t)(b * 2048 + r) * 2048 + h * 128;
        float4 o0, o1;
        o0.x = accO[i][0] * inv; o0.y = accO[i][1] * inv;
        o0.z = accO[i][2] * inv; o0.w = accO[i][3] * inv;
        o1.x = accO[i][4] * inv; o1.y = accO[i][5] * inv;
        o1.z = accO[i][6] * inv; o1.w = accO[i][7] * inv;
        *(float4*)(orow + tx * 4) = o0;
        *(float4*)(orow + 64 + tx * 4) = o1;
    }
}

// ---------------------------------------------------------------------------
extern "C" void kernel_launch(void* const* d_in, const int* in_sizes, int n_in,
                              void* d_out, int out_size, void* d_ws, size_t ws_size,
                              hipStream_t stream) {
    const float* hs = (const float*)d_in[0];  // [2,2048,2048]
    const float* k  = (const float*)d_in[1];  // [2,4,2048,128]
    const float* v  = (const float*)d_in[2];  // [2,4,2048,128]
    const float* wq = (const float*)d_in[3];  // [2048,2048]
    const float* bq = (const float*)d_in[4];  // [2048]
    const float* wp = (const float*)d_in[5];  // [2048,2048]
    const float* bp = (const float*)d_in[6];  // [2048]
    float* out = (float*)d_out;               // [2,2048,2048]

    const int M = 4096, N = 2048, K = 2048;   // M = B*S
    float* qbuf = (float*)d_ws;               // [M, 2048] fp32 (33.5 MB)
    float* abuf = qbuf + (size_t)M * N;       // [M, 2048] fp32 (33.5 MB)

    dim3 blk(256);
    dim3 gGemm(N / 128, M / 128);             // 16 x 32
    gemm_nt_bias<<<gGemm, blk, 0, stream>>>(hs, wq, bq, qbuf, M, N, K);

    dim3 gAttn(2048 / 64, 32);                // q-blocks x (B*NH)
    attn_flash<<<gAttn, blk, 0, stream>>>(qbuf, k, v, abuf);

    gemm_nt_bias<<<gGemm, blk, 0, stream>>>(abuf, wp, bp, out, M, N, K);
}

// Round 2
// 323.810 us; speedup vs baseline: 7.0442x; 7.0442x over previous
//
#include <hip/hip_runtime.h>
#include <math.h>

// B=2, S=2048, H=2048, NH=16, KVH=4, D=128, layer 5.
// All matmul stages on mfma_f32_16x16x32_bf16 (fp32 accum).
// valid logit = qk / sqrt(128); masked logit = -65504*6 (finite, exp -> 0).

#define RSQ128 0.08838834764831845f
#define MASK6  (-393024.0f)

typedef __attribute__((ext_vector_type(8))) short short8;   // 8 bf16 = 4 VGPR
typedef __attribute__((ext_vector_type(4))) float f32x4;    // MFMA C/D

static __device__ __forceinline__ unsigned short f2bf(float x) {
    union { float f; unsigned u; } v; v.f = x;
    unsigned r = v.u + 0x7FFFu + ((v.u >> 16) & 1u);   // RNE
    return (unsigned short)(r >> 16);
}

static __device__ __forceinline__ void gl_lds16(const void* g, void* l) {
    __builtin_amdgcn_global_load_lds(
        (const __attribute__((address_space(1))) void*)g,
        (__attribute__((address_space(3))) void*)l, 16, 0, 0);
}

// ---------------------------------------------------------------------------
// fp32 -> bf16 convert, 8 elems/thread
// ---------------------------------------------------------------------------
__global__ void cvt_bf16(const float* __restrict__ in, unsigned short* __restrict__ out) {
    const int i = (blockIdx.x * 256 + threadIdx.x) * 8;
    const float4 a = *(const float4*)(in + i);
    const float4 b = *(const float4*)(in + i + 4);
    short8 o;
    o[0] = (short)f2bf(a.x); o[1] = (short)f2bf(a.y);
    o[2] = (short)f2bf(a.z); o[3] = (short)f2bf(a.w);
    o[4] = (short)f2bf(b.x); o[5] = (short)f2bf(b.y);
    o[6] = (short)f2bf(b.z); o[7] = (short)f2bf(b.w);
    *(short8*)(out + i) = o;
}

// ---------------------------------------------------------------------------
// V [8][2048][128] fp32 -> Vt [8][128][2048] bf16 (per (b,kvh) transpose)
// ---------------------------------------------------------------------------
__global__ void vtrans_bf16(const float* __restrict__ V, unsigned short* __restrict__ Vt) {
    __shared__ float Ts[64][65];
    const int t = threadIdx.x;
    const int s0 = blockIdx.x * 64, d0 = blockIdx.y * 64;
    const float* src = V + (size_t)blockIdx.z * 2048 * 128;
    unsigned short* dst = Vt + (size_t)blockIdx.z * 128 * 2048;
#pragma unroll
    for (int p = 0; p < 4; ++p) {
        const int f = p * 256 + t, r = f >> 4, cq = f & 15;
        const float4 v = *(const float4*)(src + (size_t)(s0 + r) * 128 + d0 + cq * 4);
        Ts[r][cq * 4 + 0] = v.x; Ts[r][cq * 4 + 1] = v.y;
        Ts[r][cq * 4 + 2] = v.z; Ts[r][cq * 4 + 3] = v.w;
    }
    __syncthreads();
#pragma unroll
    for (int p = 0; p < 2; ++p) {
        const int f = p * 256 + t, dr = f >> 3, c = f & 7;
        short8 o;
#pragma unroll
        for (int j = 0; j < 8; ++j) o[j] = (short)f2bf(Ts[c * 8 + j][dr]);
        *(short8*)(dst + (size_t)(d0 + dr) * 2048 + s0 + c * 8) = o;
    }
}

// ---------------------------------------------------------------------------
// NT GEMM bf16 MFMA: C[m,n] = sum_k A[m,k] W[n,k] + bias[n]
// 128x128 tile, BK=32, global_load_lds 16B staging, 4 waves * (4x4) 16x16 tiles
// ---------------------------------------------------------------------------
template <bool BF16OUT>
__global__ __launch_bounds__(256, 2) void gemm_nt_mfma(
    const unsigned short* __restrict__ A,  // [M,K] bf16
    const unsigned short* __restrict__ W,  // [N,K] bf16
    const float* __restrict__ bias,        // [N] fp32
    void* __restrict__ Cout, int M, int N, int K)
{
    __shared__ __align__(16) unsigned short As[128 * 32];
    __shared__ __align__(16) unsigned short Ws[128 * 32];
    const int tid = threadIdx.x, lane = tid & 63, w = tid >> 6;
    const int wm = w & 1, wn = w >> 1;
    const int m0 = blockIdx.y * 128, n0 = blockIdx.x * 128;
    const int r0 = tid >> 2, c0 = tid & 3;   // staging: row, 16B-chunk in 64B row

    const unsigned short* Ag = A + (size_t)(m0 + r0) * K + c0 * 8;
    const unsigned short* Wg = W + (size_t)(n0 + r0) * K + c0 * 8;

    f32x4 acc[4][4];
#pragma unroll
    for (int i = 0; i < 4; ++i)
#pragma unroll
        for (int j = 0; j < 4; ++j) acc[i][j] = (f32x4){0.f, 0.f, 0.f, 0.f};

    const int lm = lane & 15, lk = (lane >> 4) * 8;

    for (int k0 = 0; k0 < K; k0 += 32) {
        __syncthreads();                      // prev tile reads done
        gl_lds16(Ag + k0,                 As + tid * 8);
        gl_lds16(Ag + (size_t)64 * K + k0, As + (tid + 256) * 8);
        gl_lds16(Wg + k0,                 Ws + tid * 8);
        gl_lds16(Wg + (size_t)64 * K + k0, Ws + (tid + 256) * 8);
        __syncthreads();                      // drains vmcnt before use

        short8 a[4], b[4];
#pragma unroll
        for (int i = 0; i < 4; ++i)
            a[i] = *(const short8*)&As[(64 * wm + 16 * i + lm) * 32 + lk];
#pragma unroll
        for (int j = 0; j < 4; ++j)
            b[j] = *(const short8*)&Ws[(64 * wn + 16 * j + lm) * 32 + lk];
#pragma unroll
        for (int i = 0; i < 4; ++i)
#pragma unroll
            for (int j = 0; j < 4; ++j)
                acc[i][j] = __builtin_amdgcn_mfma_f32_16x16x32_bf16(a[i], b[j], acc[i][j], 0, 0, 0);
    }

    float bv[4];
#pragma unroll
    for (int j = 0; j < 4; ++j) bv[j] = bias[n0 + 64 * wn + 16 * j + lm];
#pragma unroll
    for (int i = 0; i < 4; ++i)
#pragma unroll
        for (int reg = 0; reg < 4; ++reg) {
            const int row = m0 + 64 * wm + 16 * i + 4 * (lane >> 4) + reg;
#pragma unroll
            for (int j = 0; j < 4; ++j) {
                const int col = n0 + 64 * wn + 16 * j + lm;
                const float v = acc[i][j][reg] + bv[j];
                if (BF16OUT) ((unsigned short*)Cout)[(size_t)row * N + col] = f2bf(v);
                else         ((float*)Cout)[(size_t)row * N + col] = v;
            }
        }
}

// ---------------------------------------------------------------------------
// Flash attention, bf16 MFMA, causal, GQA 4:1.
// Br=Bc=64. 4 waves, wave w owns q-rows 16w..16w+15.
// LDS tiles chunk-XOR-swizzled (16B chunks): reads/writes <=2-way aliasing.
// ---------------------------------------------------------------------------
__global__ __launch_bounds__(256, 2) void attn_mfma(
    const unsigned short* __restrict__ Q,   // [4096][2048] bf16 (qbuf)
    const unsigned short* __restrict__ Kg_, // [2,4,2048,128] bf16
    const unsigned short* __restrict__ Vt,  // [2,4,128,2048] bf16
    unsigned short* __restrict__ O)         // [4096][2048] bf16
{
    __shared__ __align__(16) unsigned short Qs[64 * 128];  // [q][16 chunks]
    __shared__ __align__(16) unsigned short Ks[64 * 128];  // [key][16 chunks]
    __shared__ __align__(16) unsigned short Vs[128 * 64];  // [d][8 chunks]
    __shared__ __align__(16) unsigned short Ps[64 * 64];   // [q][8 chunks]

    const int tid = threadIdx.x, lane = tid & 63, w = tid >> 6;
    // heavy blocks first: qb descending major
    const int bid = blockIdx.x;
    const int qb = 31 - (bid >> 5);
    const int bh = bid & 31;
    const int s0 = qb * 64;
    const int b = bh >> 4, h = bh & 15, kh = h >> 2;

    const unsigned short* Qg = Q + (size_t)(b * 2048 + s0) * 2048 + h * 128;
    const unsigned short* Kb = Kg_ + (size_t)(b * 4 + kh) * 2048 * 128;
    const unsigned short* Vg = Vt + (size_t)(b * 4 + kh) * 128 * 2048;

    // ---- stage Q once (row=q, 16 chunks, swizzle c ^ (q&15)) ----
#pragma unroll
    for (int p = 0; p < 4; ++p) {
        const int f = p * 256 + tid, r = f >> 4, c = f & 15;
        const short8 v = *(const short8*)(Qg + (size_t)r * 2048 + c * 8);
        *(short8*)&Qs[(r * 16 + (c ^ (r & 15))) * 8] = v;
    }

    f32x4 aO[8];
#pragma unroll
    for (int nt = 0; nt < 8; ++nt) aO[nt] = (f32x4){0.f, 0.f, 0.f, 0.f};
    float m_[4], l_[4];
#pragma unroll
    for (int r = 0; r < 4; ++r) { m_[r] = -INFINITY; l_[r] = 0.f; }

    const int lm = lane & 15;
    const int lg = lane >> 4;

    for (int t0 = 0; t0 <= s0; t0 += 64) {
        __syncthreads();   // prev iter K/V/P reads done
        // ---- stage K tile ----
#pragma unroll
        for (int p = 0; p < 4; ++p) {
            const int f = p * 256 + tid, r = f >> 4, c = f & 15;
            const short8 v = *(const short8*)(Kb + (size_t)(t0 + r) * 128 + c * 8);
            *(short8*)&Ks[(r * 16 + (c ^ (r & 15))) * 8] = v;
        }
        // ---- stage Vt tile (row=d, 8 chunks of 8 keys, swizzle c ^ (d&7)) ----
#pragma unroll
        for (int p = 0; p < 4; ++p) {
            const int f = p * 256 + tid, d = f >> 3, c = f & 7;
            const short8 v = *(const short8*)(Vg + (size_t)d * 2048 + t0 + c * 8);
            *(short8*)&Vs[(d * 8 + (c ^ (d & 7))) * 8] = v;
        }
        __syncthreads();

        // ---- S = Q K^T  (wave rows 16w..16w+15, 4 col tiles) ----
        f32x4 s4[4];
#pragma unroll
        for (int jt = 0; jt < 4; ++jt) s4[jt] = (f32x4){0.f, 0.f, 0.f, 0.f};
#pragma unroll
        for (int k0 = 0; k0 < 128; k0 += 32) {
            const int ca = (k0 >> 3) + lg;
            const int mq = 16 * w + lm;
            const short8 a = *(const short8*)&Qs[(mq * 16 + (ca ^ (mq & 15))) * 8];
#pragma unroll
            for (int jt = 0; jt < 4; ++jt) {
                const int nk = 16 * jt + lm;
                const short8 bf = *(const short8*)&Ks[(nk * 16 + (ca ^ (nk & 15))) * 8];
                s4[jt] = __builtin_amdgcn_mfma_f32_16x16x32_bf16(a, bf, s4[jt], 0, 0, 0);
            }
        }

        // ---- mask + scale + row max (rows r: q_local = 16w + 4*lg + r) ----
        float pm[4];
#pragma unroll
        for (int r = 0; r < 4; ++r) {
            const int ql = 16 * w + 4 * lg + r;
            float mx = -1e30f;
#pragma unroll
            for (int jt = 0; jt < 4; ++jt) {
                const int kl = 16 * jt + lm;
                const float v = (t0 + kl > s0 + ql) ? MASK6 : s4[jt][r] * RSQ128;
                s4[jt][r] = v;
                mx = fmaxf(mx, v);
            }
            pm[r] = mx;
        }
#pragma unroll
        for (int off = 1; off < 16; off <<= 1)
#pragma unroll
            for (int r = 0; r < 4; ++r)
                pm[r] = fmaxf(pm[r], __shfl_xor(pm[r], off, 16));

        float al[4];
#pragma unroll
        for (int r = 0; r < 4; ++r) {
            const float mn = fmaxf(m_[r], pm[r]);
            al[r] = __expf(m_[r] - mn);   // 0 on first tile (m_=-inf)
            m_[r] = mn;
        }
#pragma unroll
        for (int nt = 0; nt < 8; ++nt)
#pragma unroll
            for (int r = 0; r < 4; ++r) aO[nt][r] *= al[r];

        // ---- P = exp(s-m) -> Ps (bf16, swizzled); row sums ----
        float ls[4];
#pragma unroll
        for (int r = 0; r < 4; ++r) {
            const int q = 16 * w + 4 * lg + r;
            float s = 0.f;
#pragma unroll
            for (int jt = 0; jt < 4; ++jt) {
                const float p = __expf(s4[jt][r] - m_[r]);
                s += p;
                const int key = 16 * jt + lm;
                Ps[q * 64 + ((key >> 3) ^ (q & 7)) * 8 + (key & 7)] = f2bf(p);
            }
            ls[r] = s;
        }
#pragma unroll
        for (int off = 1; off < 16; off <<= 1)
#pragma unroll
            for (int r = 0; r < 4; ++r) ls[r] += __shfl_xor(ls[r], off, 16);
#pragma unroll
        for (int r = 0; r < 4; ++r) l_[r] = l_[r] * al[r] + ls[r];

        __syncthreads();   // Ps visible to all waves

        // ---- O += P V  (A=Ps rows 16w.., B=Vs, 8 d-tiles) ----
#pragma unroll
        for (int k0 = 0; k0 < 64; k0 += 32) {
            const int ca = (k0 >> 3) + lg;
            const int mq = 16 * w + lm;
            const short8 a = *(const short8*)&Ps[(mq * 8 + (ca ^ (mq & 7))) * 8];
#pragma unroll
            for (int nt = 0; nt < 8; ++nt) {
                const int nd = 16 * nt + lm;
                const short8 bf = *(const short8*)&Vs[(nd * 8 + (ca ^ (nd & 7))) * 8];
                aO[nt] = __builtin_amdgcn_mfma_f32_16x16x32_bf16(a, bf, aO[nt], 0, 0, 0);
            }
        }
    }

    // ---- epilogue: O / l -> bf16 ----
#pragma unroll
    for (int r = 0; r < 4; ++r) {
        const float inv = 1.0f / l_[r];
        const int row = s0 + 16 * w + 4 * lg + r;
        unsigned short* op = O + (size_t)(b * 2048 + row) * 2048 + h * 128;
#pragma unroll
        for (int nt = 0; nt < 8; ++nt)
            op[16 * nt + lm] = f2bf(aO[nt][r] * inv);
    }
}

// ---------------------------------------------------------------------------
extern "C" void kernel_launch(void* const* d_in, const int* in_sizes, int n_in,
                              void* d_out, int out_size, void* d_ws, size_t ws_size,
                              hipStream_t stream) {
    const float* hs = (const float*)d_in[0];
    const float* k  = (const float*)d_in[1];
    const float* v  = (const float*)d_in[2];
    const float* wq = (const float*)d_in[3];
    const float* bq = (const float*)d_in[4];
    const float* wp = (const float*)d_in[5];
    const float* bp = (const float*)d_in[6];
    float* out = (float*)d_out;

    // ws layout (bf16 elements); wpb aliases hsb (dead after GEMM1). 67.1 MB.
    unsigned short* hsb  = (unsigned short*)d_ws;     // 8,388,608
    unsigned short* wqb  = hsb  + 8388608;            // 4,194,304
    unsigned short* kb   = wqb  + 4194304;            // 2,097,152
    unsigned short* vtb  = kb   + 2097152;            // 2,097,152
    unsigned short* qbuf = vtb  + 2097152;            // 8,388,608
    unsigned short* abuf = qbuf + 8388608;            // 8,388,608
    unsigned short* wpb  = hsb;                       // alias

    cvt_bf16<<<4096, 256, 0, stream>>>(hs, hsb);
    cvt_bf16<<<2048, 256, 0, stream>>>(wq, wqb);
    cvt_bf16<<<1024, 256, 0, stream>>>(k, kb);
    vtrans_bf16<<<dim3(32, 2, 8), 256, 0, stream>>>(v, vtb);

    dim3 gG(16, 32);
    gemm_nt_mfma<true><<<gG, 256, 0, stream>>>(hsb, wqb, bq, qbuf, 4096, 2048, 2048);
    cvt_bf16<<<2048, 256, 0, stream>>>(wp, wpb);
    attn_mfma<<<1024, 256, 0, stream>>>(qbuf, kb, vtb, abuf);
    gemm_nt_mfma<false><<<gG, 256, 0, stream>>>(abuf, wpb, bp, out, 4096, 2048, 2048);
}